// Round 16
// baseline (56.181 us; speedup 1.0000x reference)
//
#include <hip/hip_runtime.h>

// Problem: out[b,h,w,i,k] = inputs[b,h,w,i] * u[i,k],
//          u[i,k] = beta[i,k]^2 / sum_k beta[i,k]^2
// Shapes: inputs (4,256,256,32) f32, beta (32,8) f32, out (...,32,8) f32.
// Memory-bound: 268 MB write + 33.5 MB read. Composite floor ~44us.
//
// Evidence (302 MB effective):
//   r11 2048 fronts, 32 w/CU            : 62.6us
//   r12  512 fronts, 8 w/CU             : 55.3us  <- best
//   r13  256 fronts, 4 w/CU             : 58.1us  (conflated: waves too low)
//   r14  512 fronts, 16 w/CU            : 55.3us  (occupancy axis saturated)
// Round-15: deconfound front count at constant 8 w/CU, and collapse the
// machine-wide write pattern to 8 dense fronts (one per XCD) via
// XCD-aware region assignment: blocks dispatch round-robin to XCDs, so
// region = (bid%8)*32 + bid/8 gives each XCD one contiguous 32 MiB sweep.
// 256 blocks x 512 threads, 1 blk/CU, 129 KiB LDS, plain stores,
// phase-separated staging.

#define DIMD 32
#define DIMK 8
#define THREADS 512
#define NBLOCKS 256
#define CHUNKS_PER_BLOCK 65536   // f32x4 output chunks per block (1 MiB)
#define IN4_PER_BLOCK    8192    // f32x4 input per block (128 KiB)

typedef float f32x4 __attribute__((ext_vector_type(4)));

__global__ __launch_bounds__(THREADS) void mass_proto_kernel(
    const float* __restrict__ inputs,
    const float* __restrict__ beta,
    float* __restrict__ out,
    int n4,       // total output f32x4 chunks
    int nelem4)   // total input f32x4s
{
    extern __shared__ __align__(16) float lds[];
    float* u  = lds;          // 256 floats (1 KiB)
    float* xf = lds + 256;    // 32768 floats (128 KiB) staged input
    f32x4* xin4 = reinterpret_cast<f32x4*>(xf);

    const int t = threadIdx.x;                  // 0..511
    // XCD-aware region assignment: blockIdx round-robins across the 8
    // XCDs, so (bid%8) IS the XCD. Give each XCD a contiguous span.
    const int region = (blockIdx.x % 8) * (NBLOCKS / 8) + blockIdx.x / 8;
    const int cbase = region * CHUNKS_PER_BLOCK;  // output chunk base
    const int ibase = region * IN4_PER_BLOCK;     // input f32x4 base

    // ---- phase 1: stage contiguous 128 KiB input slice into LDS ----
    const f32x4* __restrict__ in4 = reinterpret_cast<const f32x4*>(inputs);
    if (ibase + IN4_PER_BLOCK <= nelem4) {
#pragma unroll
        for (int j = 0; j < IN4_PER_BLOCK / THREADS; ++j)   // 16 loads in flight
            xin4[j * THREADS + t] = in4[ibase + j * THREADS + t];
    } else {
#pragma unroll
        for (int j = 0; j < IN4_PER_BLOCK / THREADS; ++j) {
            const int g = ibase + j * THREADS + t;
            xin4[j * THREADS + t] = (g < nelem4) ? in4[g] : (f32x4)0.f;
        }
    }

    // ---- u[i,k] = beta^2 / rowsum(beta^2) via intra-row shuffles ----
    if (t < DIMD * DIMK) {
        const float bv = beta[t];
        const float s2 = bv * bv;
        float sum = s2;
        sum += __shfl_xor(sum, 1);
        sum += __shfl_xor(sum, 2);
        sum += __shfl_xor(sum, 4);
        u[t] = s2 / sum;
    }
    __syncthreads();                            // xin + u both ready

    // chunk index mod 64 == t mod 64 (bases and THREADS all %64==0)
    const f32x4 uu = reinterpret_cast<const f32x4*>(u)[t & 63];
    f32x4* __restrict__ out4 = reinterpret_cast<f32x4*>(out) + cbase;
    const int th = t >> 1;                      // LDS slot (2-way broadcast, free)

    // ---- phase 2: pure sequential write sweep over this block's 1 MiB ----
    if (cbase + CHUNKS_PER_BLOCK <= n4) {
#pragma unroll 8
        for (int j = 0; j < CHUNKS_PER_BLOCK / THREADS; ++j)   // 128 trips
            out4[j * THREADS + t] = xf[j * (THREADS / 2) + th] * uu;
    } else {
#pragma unroll 8
        for (int j = 0; j < CHUNKS_PER_BLOCK / THREADS; ++j) {
            const int c = j * THREADS + t;
            if (cbase + c < n4) out4[c] = xf[j * (THREADS / 2) + th] * uu;
        }
    }
}

extern "C" void kernel_launch(void* const* d_in, const int* in_sizes, int n_in,
                              void* d_out, int out_size, void* d_ws, size_t ws_size,
                              hipStream_t stream) {
    const float* inputs = (const float*)d_in[0];  // (4,256,256,32)
    const float* beta   = (const float*)d_in[1];  // (32,8)
    float* out = (float*)d_out;                   // (4,256,256,32,8)

    const int n4 = out_size / 4;                  // 16,777,216 chunks
    const int nelem4 = in_sizes[0] / 4;           // 2,097,152 input f32x4
    const size_t shmem = (256 + IN4_PER_BLOCK * 4) * sizeof(float);  // 129 KiB

    mass_proto_kernel<<<NBLOCKS, THREADS, shmem, stream>>>(inputs, beta, out, n4, nelem4);
}